// Round 1
// baseline (9111.163 us; speedup 1.0000x reference)
//
#include <hip/hip_runtime.h>

#define S_ 2048
#define B_ 64
#define D_ 512
#define H_ 512
#define BH_ (B_*H_)

typedef __attribute__((ext_vector_type(4))) float fx4;
typedef __attribute__((ext_vector_type(8))) short sx8;
typedef __attribute__((ext_vector_type(4))) unsigned int ux4;
typedef __attribute__((ext_vector_type(2))) unsigned int ux2;
typedef __attribute__((ext_vector_type(4))) unsigned short usx4;

__device__ __forceinline__ unsigned short f2bf(float f) {
    union { float f; unsigned int u; } v; v.f = f;
    return (unsigned short)((v.u + 0x7fffu + ((v.u >> 16) & 1u)) >> 16);
}
__device__ __forceinline__ float bf2f(unsigned short b) {
    union { float f; unsigned int u; } v; v.u = ((unsigned int)b) << 16;
    return v.f;
}

// ---------------------------------------------------------------------------
// Phase 1: input projections. xr/xz -> packed bf16 halves of d_out's u32 slot
// (later overwritten by the output h), xn -> bf16 in ws. Biases b_i* included.
// Grid: (1024 M-tiles of 128 rows (2 t x 64 b), 12 N-tiles of 128 cols over
// [r|z|n] x 512). Block: 256 threads = 4 waves, each wave a 64x64 quadrant.
// ---------------------------------------------------------------------------
__global__ __launch_bounds__(256) void proj_k(
    const float* __restrict__ x,
    const float* __restrict__ Wir, const float* __restrict__ bir,
    const float* __restrict__ Wiz, const float* __restrict__ biz,
    const float* __restrict__ Win, const float* __restrict__ bin_,
    unsigned short* __restrict__ outp_u16,   // d_out viewed as u16
    unsigned short* __restrict__ xn)         // ws bf16 [S][B][H]
{
    const int nt   = blockIdx.y;            // 0..11
    const int gate = nt >> 2;               // 0=r, 1=z, 2=n
    const float* W  = (gate == 0) ? Wir : ((gate == 1) ? Wiz : Win);
    const float* bi = (gate == 0) ? bir : ((gate == 1) ? biz : bin_);
    const int jbase = (nt & 3) * 128;       // col base within gate
    const int m0 = blockIdx.x * 128;
    const int t0 = blockIdx.x * 2;

    __shared__ __align__(16) unsigned short As[128][88];
    __shared__ __align__(16) unsigned short Bs[128][88];

    const int tid  = threadIdx.x;
    const int lane = tid & 63;
    const int wv   = tid >> 6;              // 0..3
    const int wm   = wv >> 1, wn = wv & 1;

    fx4 z4 = {0.f, 0.f, 0.f, 0.f};
    fx4 acc[4][4];
#pragma unroll
    for (int i = 0; i < 4; ++i)
#pragma unroll
        for (int j = 0; j < 4; ++j) acc[i][j] = z4;

    const int rr = tid >> 4;                // 0..15
    const int c4 = (tid & 15) * 4;

    for (int kb = 0; kb < 8; ++kb) {
        const int k0 = kb * 64;
#pragma unroll
        for (int pass = 0; pass < 8; ++pass) {
            const int r = pass * 16 + rr;
            // A: x[b][t][k], row r -> b=r&63, t=t0+(r>>6)
            const int bb = r & 63, tt = t0 + (r >> 6);
            const float* srcA = x + ((size_t)bb * S_ + tt) * D_ + k0 + c4;
            fx4 va = *(const fx4*)srcA;
            usx4 pa = { f2bf(va.x), f2bf(va.y), f2bf(va.z), f2bf(va.w) };
            *(usx4*)&As[r][c4] = pa;
            // B: W[j][k], j = jbase + r
            const float* srcB = W + (size_t)(jbase + r) * D_ + k0 + c4;
            fx4 vb = *(const fx4*)srcB;
            usx4 pb = { f2bf(vb.x), f2bf(vb.y), f2bf(vb.z), f2bf(vb.w) };
            *(usx4*)&Bs[r][c4] = pb;
        }
        __syncthreads();
#pragma unroll
        for (int kk = 0; kk < 64; kk += 32) {
            const int kloc = kk + (lane >> 4) * 8;
            sx8 af[4], bfv[4];
#pragma unroll
            for (int i = 0; i < 4; ++i)
                af[i] = *(const sx8*)&As[wm * 64 + i * 16 + (lane & 15)][kloc];
#pragma unroll
            for (int i = 0; i < 4; ++i)
                bfv[i] = *(const sx8*)&Bs[wn * 64 + i * 16 + (lane & 15)][kloc];
#pragma unroll
            for (int mi = 0; mi < 4; ++mi)
#pragma unroll
                for (int ni = 0; ni < 4; ++ni)
                    acc[mi][ni] = __builtin_amdgcn_mfma_f32_16x16x32_bf16(
                        af[mi], bfv[ni], acc[mi][ni], 0, 0, 0);
        }
        __syncthreads();
    }

    // Epilogue: C/D layout col=lane&15, row=(lane>>4)*4+reg (verified m89)
    const int cold = lane & 15;
    const int rowq = (lane >> 4) * 4;
#pragma unroll
    for (int ni = 0; ni < 4; ++ni) {
        const int J = jbase + wn * 64 + ni * 16 + cold;   // within-gate col
        const float bb = bi[J];
#pragma unroll
        for (int mi = 0; mi < 4; ++mi) {
#pragma unroll
            for (int reg = 0; reg < 4; ++reg) {
                const int R = m0 + wm * 64 + mi * 16 + rowq + reg;
                const int t = R >> 6, b = R & 63;
                const float val = acc[mi][ni][reg] + bb;
                const size_t e = (size_t)t * BH_ + (size_t)b * H_ + J;
                if (gate < 2) outp_u16[e * 2 + gate] = f2bf(val);  // r->lo, z->hi
                else          xn[e] = f2bf(val);
            }
        }
    }
}

// ---------------------------------------------------------------------------
// Phase 2: persistent recurrent kernel. 256 blocks = 16 groups x 16 members.
// Group g handles batches 4g..4g+3; member m owns output cols [32m,32m+32).
// Weights: 3 x 16 MFMA B-frags per wave, VGPR-resident. h exchanged through
// IF-coherent tagged 16B packets [tag | 2x(bf16 pair) | tag]; replay-safe.
// Block: 192 threads. Waves 0,1 = matvec+gates (16 cols each); wave 2 =
// poll/unpack + pack/store.
// ---------------------------------------------------------------------------
__global__ __launch_bounds__(192, 1) void gru_k(
    float* out,                              // d_out: read packed xr/xz, write h
    const unsigned short* __restrict__ xn,   // ws bf16
    unsigned int* pkt,                       // ws packet region
    const float* Whr, const float* bhr,
    const float* Whz, const float* bhz,
    const float* Whn, const float* bhn)
{
    const int tid = threadIdx.x, lane = tid & 63, wv = tid >> 6;
    const int bid = blockIdx.x;
    const int g = bid & 15;      // group (members share XCD under %8 round-robin)
    const int m = bid >> 4;      // member 0..15
    const int c0 = m * 32;

    __shared__ __align__(16) unsigned short hst[4][520];  // h state, bf16, padded
    __shared__ __align__(16) float hnew[4][32];

    for (int i = tid; i < 4 * 520; i += 192) ((unsigned short*)hst)[i] = 0;

    // --- load weight B-fragments into registers (waves 0,1) ---
    sx8 wfr[16], wfz[16], wfn[16];
    float bhr_v = 0.f, bhz_v = 0.f, bhn_v = 0.f;
    float hprev[4] = {0.f, 0.f, 0.f, 0.f};
    if (wv < 2) {
        const int j = c0 + wv * 16 + (lane & 15);
        const int kbase = (lane >> 4) * 8;
#pragma unroll
        for (int kc = 0; kc < 16; ++kc) {
            const int k0 = kc * 32 + kbase;
            const float* pr = Whr + (size_t)j * H_ + k0;
            const float* pz = Whz + (size_t)j * H_ + k0;
            const float* pn = Whn + (size_t)j * H_ + k0;
            sx8 fr, fz, fn;
#pragma unroll
            for (int q = 0; q < 8; ++q) {
                fr[q] = (short)f2bf(pr[q]);
                fz[q] = (short)f2bf(pz[q]);
                fn[q] = (short)f2bf(pn[q]);
            }
            wfr[kc] = fr; wfz[kc] = fz; wfn[kc] = fn;
        }
        if (lane < 16) {
            const int jj = c0 + wv * 16 + lane;
            bhr_v = bhr[jj]; bhz_v = bhz[jj]; bhn_v = bhn[jj];
        }
    }
    __syncthreads();

    for (int t = 0; t < S_; ++t) {
        // Phase A: waves 0,1 prefetch gate inputs; wave 2 polls+unpacks h(t)
        unsigned int xzv[4] = {0, 0, 0, 0};
        float xnv[4] = {0.f, 0.f, 0.f, 0.f};
        if (wv < 2) {
            if (lane < 16) {
                const int j = c0 + wv * 16 + lane;
#pragma unroll
                for (int r = 0; r < 4; ++r) {
                    const size_t e = (size_t)t * BH_ + (size_t)(4 * g + r) * H_ + j;
                    xzv[r] = __float_as_uint(out[e]);   // same pointer as h-store: ordered
                    xnv[r] = bf2f(xn[e]);
                }
            }
        } else if (t > 0) {
            const int b = lane >> 4;      // batch within group
            const int mp = lane & 15;     // producing member
            const unsigned int ex = (unsigned int)(t - 1);
            const unsigned int* base =
                pkt + (((size_t)(((t - 1) & 1) * 64 + 4 * g + b)) * 128 + (size_t)mp * 8) * 4;
            ux4 q0, q1, q2, q3, q4, q5, q6, q7;
            for (;;) {
                asm volatile(
                    "global_load_dwordx4 %0, %8, off sc0 sc1\n\t"
                    "global_load_dwordx4 %1, %8, off offset:16 sc0 sc1\n\t"
                    "global_load_dwordx4 %2, %8, off offset:32 sc0 sc1\n\t"
                    "global_load_dwordx4 %3, %8, off offset:48 sc0 sc1\n\t"
                    "global_load_dwordx4 %4, %8, off offset:64 sc0 sc1\n\t"
                    "global_load_dwordx4 %5, %8, off offset:80 sc0 sc1\n\t"
                    "global_load_dwordx4 %6, %8, off offset:96 sc0 sc1\n\t"
                    "global_load_dwordx4 %7, %8, off offset:112 sc0 sc1\n\t"
                    "s_waitcnt vmcnt(0)"
                    : "=&v"(q0), "=&v"(q1), "=&v"(q2), "=&v"(q3),
                      "=&v"(q4), "=&v"(q5), "=&v"(q6), "=&v"(q7)
                    : "v"(base)
                    : "memory");
                unsigned int bad =
                    (q0.x ^ ex) | (q0.w ^ ex) | (q1.x ^ ex) | (q1.w ^ ex) |
                    (q2.x ^ ex) | (q2.w ^ ex) | (q3.x ^ ex) | (q3.w ^ ex) |
                    (q4.x ^ ex) | (q4.w ^ ex) | (q5.x ^ ex) | (q5.w ^ ex) |
                    (q6.x ^ ex) | (q6.w ^ ex) | (q7.x ^ ex) | (q7.w ^ ex);
                if (bad == 0u) break;
            }
            ux2 w;
            w.x = q0.y; w.y = q0.z; *(ux2*)&hst[b][32 * mp + 0]  = w;
            w.x = q1.y; w.y = q1.z; *(ux2*)&hst[b][32 * mp + 4]  = w;
            w.x = q2.y; w.y = q2.z; *(ux2*)&hst[b][32 * mp + 8]  = w;
            w.x = q3.y; w.y = q3.z; *(ux2*)&hst[b][32 * mp + 12] = w;
            w.x = q4.y; w.y = q4.z; *(ux2*)&hst[b][32 * mp + 16] = w;
            w.x = q5.y; w.y = q5.z; *(ux2*)&hst[b][32 * mp + 20] = w;
            w.x = q6.y; w.y = q6.z; *(ux2*)&hst[b][32 * mp + 24] = w;
            w.x = q7.y; w.y = q7.z; *(ux2*)&hst[b][32 * mp + 28] = w;
        }
        __syncthreads();

        // Phase B: matvecs + gates (waves 0,1)
        if (wv < 2) {
            fx4 z4 = {0.f, 0.f, 0.f, 0.f};
            fx4 ar = z4, az = z4, an = z4;
            const int brow = lane & 3;           // rows 4..15 = duplicates, ignored
            const int kb2 = (lane >> 4) * 8;
#pragma unroll
            for (int kc = 0; kc < 16; ++kc) {
                sx8 a = *(const sx8*)&hst[brow][kc * 32 + kb2];
                ar = __builtin_amdgcn_mfma_f32_16x16x32_bf16(a, wfr[kc], ar, 0, 0, 0);
                az = __builtin_amdgcn_mfma_f32_16x16x32_bf16(a, wfz[kc], az, 0, 0, 0);
                an = __builtin_amdgcn_mfma_f32_16x16x32_bf16(a, wfn[kc], an, 0, 0, 0);
            }
            if (lane < 16) {
                const int j = c0 + wv * 16 + lane;
#pragma unroll
                for (int r = 0; r < 4; ++r) {
                    const float arx = ar[r] + bf2f((unsigned short)(xzv[r] & 0xffffu)) + bhr_v;
                    const float azx = az[r] + bf2f((unsigned short)(xzv[r] >> 16)) + bhz_v;
                    const float anv = an[r] + bhn_v;
                    const float rg = 1.f / (1.f + __expf(-arx));
                    const float zg = 1.f / (1.f + __expf(-azx));
                    const float nn = tanhf(xnv[r] + rg * anv);
                    const float hv = (1.f - zg) * nn + zg * hprev[r];
                    hprev[r] = hv;
                    const size_t e = (size_t)t * BH_ + (size_t)(4 * g + r) * H_ + j;
                    out[e] = hv;
                    if (t == S_ - 1)
                        out[(size_t)S_ * BH_ + (size_t)(4 * g + r) * H_ + j] = hv;
                    hnew[r][wv * 16 + lane] = hv;
                }
            }
        }
        __syncthreads();

        // Phase C: wave 2 packs + publishes this block's h slice
        if (wv == 2 && lane < 32) {
            const int r = lane >> 3, p = lane & 7;
            const float h0 = hnew[r][4 * p + 0], h1 = hnew[r][4 * p + 1];
            const float h2 = hnew[r][4 * p + 2], h3 = hnew[r][4 * p + 3];
            const unsigned int w0 = (unsigned int)f2bf(h0) | ((unsigned int)f2bf(h1) << 16);
            const unsigned int w1 = (unsigned int)f2bf(h2) | ((unsigned int)f2bf(h3) << 16);
            ux4 pk; pk.x = (unsigned int)t; pk.y = w0; pk.z = w1; pk.w = (unsigned int)t;
            unsigned int* addr =
                pkt + (((size_t)((t & 1) * 64 + 4 * g + r)) * 128 + (size_t)m * 8 + p) * 4;
            asm volatile("global_store_dwordx4 %0, %1, off sc0 sc1"
                         :: "v"(addr), "v"(pk) : "memory");
        }
    }
}

extern "C" void kernel_launch(void* const* d_in, const int* in_sizes, int n_in,
                              void* d_out, int out_size, void* d_ws, size_t ws_size,
                              hipStream_t stream) {
    (void)in_sizes; (void)n_in; (void)out_size; (void)ws_size;
    const float* x    = (const float*)d_in[0];
    const float* Wir  = (const float*)d_in[1];
    const float* bir  = (const float*)d_in[2];
    const float* Whr  = (const float*)d_in[3];
    const float* bhr  = (const float*)d_in[4];
    const float* Wiz  = (const float*)d_in[5];
    const float* biz  = (const float*)d_in[6];
    const float* Whz  = (const float*)d_in[7];
    const float* bhz  = (const float*)d_in[8];
    const float* Win  = (const float*)d_in[9];
    const float* bin_ = (const float*)d_in[10];
    const float* Whn  = (const float*)d_in[11];
    const float* bhn  = (const float*)d_in[12];

    unsigned short* xn = (unsigned short*)d_ws;                       // 128 MiB
    unsigned int* pkt = (unsigned int*)((char*)d_ws + (size_t)S_ * BH_ * 2);  // 256 KiB

    proj_k<<<dim3(1024, 12, 1), 256, 0, stream>>>(
        x, Wir, bir, Wiz, biz, Win, bin_, (unsigned short*)d_out, xn);
    gru_k<<<dim3(256, 1, 1), 192, 0, stream>>>(
        (float*)d_out, xn, pkt, Whr, bhr, Whz, bhz, Whn, bhn);
}

// Round 2
// 4780.898 us; speedup vs baseline: 1.9057x; 1.9057x over previous
//
#include <hip/hip_runtime.h>

#define S_ 2048
#define B_ 64
#define D_ 512
#define H_ 512
#define BH_ (B_*H_)
#define NMEM 8

typedef __attribute__((ext_vector_type(4))) float fx4;
typedef __attribute__((ext_vector_type(8))) short sx8;
typedef __attribute__((ext_vector_type(4))) unsigned int ux4;
typedef __attribute__((ext_vector_type(2))) unsigned int ux2;

__device__ __forceinline__ unsigned short f2bf(float f) {
    union { float f; unsigned int u; } v; v.f = f;
    return (unsigned short)((v.u + 0x7fffu + ((v.u >> 16) & 1u)) >> 16);
}
__device__ __forceinline__ float bf2f(unsigned short b) {
    union { float f; unsigned int u; } v; v.u = ((unsigned int)b) << 16;
    return v.f;
}
__device__ __forceinline__ unsigned int cvtpk(float a, float b) {
    unsigned int r;
    asm("v_cvt_pk_bf16_f32 %0, %1, %2" : "=v"(r) : "v"(a), "v"(b));
    return r;
}

// ---------------------------------------------------------------------------
// Phase 1: input projections. xr/xz -> packed bf16 halves of d_out's u32 slot
// (read-before-overwrite by gru_k), xn -> bf16 in ws. Grid swapped so the 12
// n-tiles of one m-tile dispatch consecutively (x m-tile served from L3), and
// bf16 staging pack uses v_cvt_pk_bf16_f32.
// ---------------------------------------------------------------------------
__global__ __launch_bounds__(256) void proj_k(
    const float* __restrict__ x,
    const float* __restrict__ Wir, const float* __restrict__ bir,
    const float* __restrict__ Wiz, const float* __restrict__ biz,
    const float* __restrict__ Win, const float* __restrict__ bin_,
    unsigned short* __restrict__ outp_u16,   // d_out viewed as u16
    unsigned short* __restrict__ xn)         // ws bf16 [S][B][H]
{
    const int nt   = blockIdx.x;            // 0..11  (fastest-varying)
    const int gate = nt >> 2;               // 0=r, 1=z, 2=n
    const float* W  = (gate == 0) ? Wir : ((gate == 1) ? Wiz : Win);
    const float* bi = (gate == 0) ? bir : ((gate == 1) ? biz : bin_);
    const int jbase = (nt & 3) * 128;       // col base within gate
    const int m0 = blockIdx.y * 128;
    const int t0 = blockIdx.y * 2;

    __shared__ __align__(16) unsigned short As[128][88];
    __shared__ __align__(16) unsigned short Bs[128][88];

    const int tid  = threadIdx.x;
    const int lane = tid & 63;
    const int wv   = tid >> 6;              // 0..3
    const int wm   = wv >> 1, wn = wv & 1;

    fx4 z4 = {0.f, 0.f, 0.f, 0.f};
    fx4 acc[4][4];
#pragma unroll
    for (int i = 0; i < 4; ++i)
#pragma unroll
        for (int j = 0; j < 4; ++j) acc[i][j] = z4;

    const int rr = tid >> 4;                // 0..15
    const int c4 = (tid & 15) * 4;

    for (int kb = 0; kb < 8; ++kb) {
        const int k0 = kb * 64;
#pragma unroll
        for (int pass = 0; pass < 8; ++pass) {
            const int r = pass * 16 + rr;
            const int bb = r & 63, tt = t0 + (r >> 6);
            const float* srcA = x + ((size_t)bb * S_ + tt) * D_ + k0 + c4;
            fx4 va = *(const fx4*)srcA;
            ux2 pa; pa.x = cvtpk(va.x, va.y); pa.y = cvtpk(va.z, va.w);
            *(ux2*)&As[r][c4] = pa;
            const float* srcB = W + (size_t)(jbase + r) * D_ + k0 + c4;
            fx4 vb = *(const fx4*)srcB;
            ux2 pb; pb.x = cvtpk(vb.x, vb.y); pb.y = cvtpk(vb.z, vb.w);
            *(ux2*)&Bs[r][c4] = pb;
        }
        __syncthreads();
#pragma unroll
        for (int kk = 0; kk < 64; kk += 32) {
            const int kloc = kk + (lane >> 4) * 8;
            sx8 af[4], bfv[4];
#pragma unroll
            for (int i = 0; i < 4; ++i)
                af[i] = *(const sx8*)&As[wm * 64 + i * 16 + (lane & 15)][kloc];
#pragma unroll
            for (int i = 0; i < 4; ++i)
                bfv[i] = *(const sx8*)&Bs[wn * 64 + i * 16 + (lane & 15)][kloc];
#pragma unroll
            for (int mi = 0; mi < 4; ++mi)
#pragma unroll
                for (int ni = 0; ni < 4; ++ni)
                    acc[mi][ni] = __builtin_amdgcn_mfma_f32_16x16x32_bf16(
                        af[mi], bfv[ni], acc[mi][ni], 0, 0, 0);
        }
        __syncthreads();
    }

    // Epilogue: C/D layout col=lane&15, row=(lane>>4)*4+reg (verified m89)
    const int cold = lane & 15;
    const int rowq = (lane >> 4) * 4;
#pragma unroll
    for (int ni = 0; ni < 4; ++ni) {
        const int J = jbase + wn * 64 + ni * 16 + cold;
        const float bb = bi[J];
#pragma unroll
        for (int mi = 0; mi < 4; ++mi) {
#pragma unroll
            for (int reg = 0; reg < 4; ++reg) {
                const int R = m0 + wm * 64 + mi * 16 + rowq + reg;
                const int t = R >> 6, b = R & 63;
                const float val = acc[mi][ni][reg] + bb;
                const size_t e = (size_t)t * BH_ + (size_t)b * H_ + J;
                if (gate < 2) outp_u16[e * 2 + gate] = f2bf(val);  // r->lo, z->hi
                else          xn[e] = f2bf(val);
            }
        }
    }
}

// ---------------------------------------------------------------------------
// Phase 2: persistent recurrent kernel. 16 groups x 8 members = 128 blocks.
// Group g: batches 4g..4g+3; member m owns cols [64m, 64m+64). 4 waves x 256
// threads; wave wv owns cols [c0+16wv, +16) for matvec/gates and batch wv for
// unpack/pack. Weights VGPR-resident (192 regs). h(t) in LDS double buffer,
// 16B-unit layout unit(b,k) = (k>>5)*16 + b*4 + ((k>>3)&3) -> contiguous
// A-fragment reads. Own cols short-circuit via LDS; other members exchanged
// through IF-coherent tagged packets [tag|8B payload|tag].
// ---------------------------------------------------------------------------
__global__ __launch_bounds__(256, 1) void gru_k(
    float* out,                              // d_out: read packed xr/xz, write h
    const unsigned short* __restrict__ xn,   // ws bf16
    unsigned int* pkt,                       // ws packet region
    const float* __restrict__ Whr, const float* __restrict__ bhr,
    const float* __restrict__ Whz, const float* __restrict__ bhz,
    const float* __restrict__ Whn, const float* __restrict__ bhn)
{
    const int tid = threadIdx.x, lane = tid & 63, wv = tid >> 6;
    const int g = blockIdx.x >> 3, m = blockIdx.x & 7;
    const int c0 = m * 64;
    const int r = lane >> 4;                 // batch row 0..3 (gates)
    const int jcol = c0 + wv * 16 + (lane & 15);
    const int bglob = 4 * g + r;

    __shared__ __align__(16) unsigned short hst[2][2048];
    for (int i = tid; i < 4096; i += 256) (&hst[0][0])[i] = 0;

    // Recurrent-weight B-fragments: j = jcol, k = kc*32 + kbase + q
    const int kbase = (lane >> 4) * 8;
    sx8 wfr[16], wfz[16], wfn[16];
#pragma unroll
    for (int kc = 0; kc < 16; ++kc) {
        const int k0 = kc * 32 + kbase;
        const float* pr = Whr + (size_t)jcol * H_ + k0;
        const float* pz = Whz + (size_t)jcol * H_ + k0;
        const float* pn = Whn + (size_t)jcol * H_ + k0;
        sx8 fr, fz, fn;
#pragma unroll
        for (int q = 0; q < 8; ++q) {
            fr[q] = (short)f2bf(pr[q]);
            fz[q] = (short)f2bf(pz[q]);
            fn[q] = (short)f2bf(pn[q]);
        }
        wfr[kc] = fr; wfz[kc] = fz; wfn[kc] = fn;
    }
    const float bhr_v = bhr[jcol], bhz_v = bhz[jcol], bhn_v = bhn[jcol];

    const size_t xoff = (size_t)bglob * H_ + jcol;
    unsigned int   xz_c  = __float_as_uint(out[xoff]);   // t=0 packed xr|xz
    unsigned short xnn_c = xn[xoff];
    float hprev = 0.f;
    __syncthreads();

    for (int t = 0; t < S_; ++t) {
        const int p1 = (t - 1) & 1, p0 = t & 1;

        // ---- phase A: poll + unpack h(t-1) from the other 7 members ----
        if (t > 0) {
            const int mp = lane >> 3, s = lane & 7;
            if (mp != m) {
                const unsigned int ex = (unsigned int)(t - 1);
                const char* pb = (const char*)pkt +
                    ((((size_t)p1 * 64 + (size_t)(4 * g + wv)) * NMEM + mp) * 256
                     + (size_t)s * 32);
                ux4 q0, q1;
                for (;;) {
                    asm volatile(
                        "global_load_dwordx4 %0, %2, off sc0 sc1\n\t"
                        "global_load_dwordx4 %1, %2, off offset:16 sc0 sc1\n\t"
                        "s_waitcnt vmcnt(0)"
                        : "=&v"(q0), "=&v"(q1) : "v"(pb) : "memory");
                    if ((((q0.x ^ ex) | (q0.w ^ ex)) |
                         ((q1.x ^ ex) | (q1.w ^ ex))) == 0u) break;
                    __builtin_amdgcn_s_sleep(1);
                }
                const int unit = (mp * 2 + (s >> 2)) * 16 + wv * 4 + (s & 3);
                ux4 w; w.x = q0.y; w.y = q0.z; w.z = q1.y; w.w = q1.z;
                *(ux4*)&hst[p1][unit * 8] = w;
            }
        }
        // prefetch x for t+1 (overlaps everything up to next phase B)
        const int tn = (t + 1 < S_) ? (t + 1) : t;
        const unsigned int   xz_n  = __float_as_uint(out[(size_t)tn * BH_ + xoff]);
        const unsigned short xnn_n = xn[(size_t)tn * BH_ + xoff];
        __syncthreads();

        // ---- phase B: matvec (48 MFMA) + gates (all 64 lanes) ----
        fx4 ar = {0.f,0.f,0.f,0.f}, az = {0.f,0.f,0.f,0.f}, an = {0.f,0.f,0.f,0.f};
#pragma unroll
        for (int kc = 0; kc < 16; ++kc) {
            sx8 a = *(const sx8*)&hst[p1][(kc * 16 + (lane & 3) * 4 + (lane >> 4)) * 8];
            ar = __builtin_amdgcn_mfma_f32_16x16x32_bf16(a, wfr[kc], ar, 0, 0, 0);
            az = __builtin_amdgcn_mfma_f32_16x16x32_bf16(a, wfz[kc], az, 0, 0, 0);
            an = __builtin_amdgcn_mfma_f32_16x16x32_bf16(a, wfn[kc], an, 0, 0, 0);
        }
        // batch b's result sits in acc reg index b on EVERY lane (rows 4q+reg, reg=batch)
        const float sr = (r == 0) ? ar[0] : (r == 1) ? ar[1] : (r == 2) ? ar[2] : ar[3];
        const float sz = (r == 0) ? az[0] : (r == 1) ? az[1] : (r == 2) ? az[2] : az[3];
        const float sn = (r == 0) ? an[0] : (r == 1) ? an[1] : (r == 2) ? an[2] : an[3];
        const float arx = sr + bf2f((unsigned short)(xz_c & 0xffffu)) + bhr_v;
        const float azx = sz + bf2f((unsigned short)(xz_c >> 16)) + bhz_v;
        const float rg = 1.f / (1.f + __expf(-arx));
        const float zg = 1.f / (1.f + __expf(-azx));
        const float nn = tanhf(bf2f(xnn_c) + rg * (sn + bhn_v));
        const float hv = (1.f - zg) * nn + zg * hprev;
        hprev = hv;
        out[(size_t)t * BH_ + xoff] = hv;
        if (t == S_ - 1) out[(size_t)S_ * BH_ + xoff] = hv;
        {   // own-column short-circuit into next step's h buffer
            const int unit = ((jcol >> 5) << 4) + r * 4 + ((jcol >> 3) & 3);
            hst[p0][unit * 8 + (jcol & 7)] = f2bf(hv);
        }
        xz_c = xz_n; xnn_c = xnn_n;
        __syncthreads();

        // ---- phase C: pack + publish own 64 cols of batch wv (tag = t) ----
        if (lane < 16) {
            const int k0 = c0 + lane * 4;
            const int unit = ((k0 >> 5) << 4) + wv * 4 + ((k0 >> 3) & 3);
            ux2 pay = *(const ux2*)&hst[p0][unit * 8 + (lane & 1) * 4];
            ux4 pk4; pk4.x = (unsigned int)t; pk4.y = pay.x; pk4.z = pay.y;
            pk4.w = (unsigned int)t;
            char* addr = (char*)pkt +
                ((((size_t)p0 * 64 + (size_t)(4 * g + wv)) * NMEM + m) * 256
                 + (size_t)lane * 16);
            asm volatile("global_store_dwordx4 %0, %1, off sc0 sc1"
                         :: "v"(addr), "v"(pk4) : "memory");
        }
    }
}

extern "C" void kernel_launch(void* const* d_in, const int* in_sizes, int n_in,
                              void* d_out, int out_size, void* d_ws, size_t ws_size,
                              hipStream_t stream) {
    (void)in_sizes; (void)n_in; (void)out_size; (void)ws_size;
    const float* x    = (const float*)d_in[0];
    const float* Wir  = (const float*)d_in[1];
    const float* bir  = (const float*)d_in[2];
    const float* Whr  = (const float*)d_in[3];
    const float* bhr  = (const float*)d_in[4];
    const float* Wiz  = (const float*)d_in[5];
    const float* biz  = (const float*)d_in[6];
    const float* Whz  = (const float*)d_in[7];
    const float* bhz  = (const float*)d_in[8];
    const float* Win  = (const float*)d_in[9];
    const float* bin_ = (const float*)d_in[10];
    const float* Whn  = (const float*)d_in[11];
    const float* bhn  = (const float*)d_in[12];

    unsigned short* xn = (unsigned short*)d_ws;                             // 128 MiB
    unsigned int* pkt = (unsigned int*)((char*)d_ws + (size_t)S_ * BH_ * 2); // 256 KiB

    proj_k<<<dim3(12, 1024, 1), 256, 0, stream>>>(
        x, Wir, bir, Wiz, biz, Win, bin_, (unsigned short*)d_out, xn);
    gru_k<<<dim3(128, 1, 1), 256, 0, stream>>>(
        (float*)d_out, xn, pkt, Whr, bhr, Whz, bhz, Whn, bhn);
}